// Round 1
// baseline (45.044 us; speedup 1.0000x reference)
//
#include <hip/hip_runtime.h>

// EntangleComplex: out_real = x_real * diag, out_imag = x_imag * diag
// diag[j] = (-1)^(number of cyclically-adjacent bit pairs set in j), j in [0,4096)
//
// Pure memory-bound elementwise sign flip. 256 MiB total traffic -> ~41us roofline.

#define NQ    12
#define DIM   4096          // 2^12
#define BATCH 4096
#define NELEM (BATCH * DIM) // 16,777,216 per array

__device__ __forceinline__ unsigned parity_sign_bit(unsigned j) {
    // bit i of k = bit (i+1)%12 of j  (cyclic rotate right by 1 over 12 bits)
    unsigned k = (j >> 1) | ((j & 1u) << 11);
    return (__popc(j & k) & 1u) << 31;   // 0x80000000 if parity odd, else 0
}

__global__ __launch_bounds__(256) void entangle_sign_kernel(
    const float4* __restrict__ xr,
    const float4* __restrict__ xi,
    float4* __restrict__ outr,
    float4* __restrict__ outi,
    int nvec)
{
    const int stride = gridDim.x * blockDim.x;
    for (int v = blockIdx.x * blockDim.x + threadIdx.x; v < nvec; v += stride) {
        const unsigned j0 = ((unsigned)v * 4u) & (DIM - 1u);  // DIM%4==0 -> 4 elems same row-chunk

        // Per-element sign bits (shared between real and imag)
        const unsigned s0 = parity_sign_bit(j0 + 0u);
        const unsigned s1 = parity_sign_bit(j0 + 1u);
        const unsigned s2 = parity_sign_bit(j0 + 2u);
        const unsigned s3 = parity_sign_bit(j0 + 3u);

        float4 r = xr[v];
        float4 m = xi[v];

        float4 ro, mo;
        ro.x = __uint_as_float(__float_as_uint(r.x) ^ s0);
        ro.y = __uint_as_float(__float_as_uint(r.y) ^ s1);
        ro.z = __uint_as_float(__float_as_uint(r.z) ^ s2);
        ro.w = __uint_as_float(__float_as_uint(r.w) ^ s3);
        mo.x = __uint_as_float(__float_as_uint(m.x) ^ s0);
        mo.y = __uint_as_float(__float_as_uint(m.y) ^ s1);
        mo.z = __uint_as_float(__float_as_uint(m.z) ^ s2);
        mo.w = __uint_as_float(__float_as_uint(m.w) ^ s3);

        outr[v] = ro;
        outi[v] = mo;
    }
}

extern "C" void kernel_launch(void* const* d_in, const int* in_sizes, int n_in,
                              void* d_out, int out_size, void* d_ws, size_t ws_size,
                              hipStream_t stream) {
    (void)in_sizes; (void)n_in; (void)d_ws; (void)ws_size; (void)out_size;

    const float4* xr = (const float4*)d_in[0];   // x_real [BATCH, DIM] fp32
    const float4* xi = (const float4*)d_in[1];   // x_imag [BATCH, DIM] fp32
    // d_in[2] = op [DIM, DIM] — diagonal, sign computed on-device, never read.

    float* out = (float*)d_out;
    float4* outr = (float4*)out;                  // output 0: real
    float4* outi = (float4*)(out + (size_t)NELEM); // output 1: imag

    const int nvec = NELEM / 4;                   // 4,194,304 float4s per array
    const int block = 256;
    const int grid = 2048;                        // grid-stride, ~8 iters/thread

    entangle_sign_kernel<<<grid, block, 0, stream>>>(xr, xi, outr, outi, nvec);
}